// Round 13
// baseline (159.375 us; speedup 1.0000x reference)
//
#include <hip/hip_runtime.h>
#include <math.h>

// B=4, H=W=64, C=256, Ck=32, N=4096, M=B*N=16384
// ws: fg bf16 [16384][64] (f=cols0..31, g=cols32..63, g pre-scaled by log2e)
//   | hmt bf16 FRAGMENT-SWIZZLED V: chunk(b, cg=c>>4, kc=key>>5) of 512 u16;
//       element (c,key) at chunk*512 + ((key>>3)&3)*128 + (c&15)*8 + (key&7)
//   | wT bf16 FRAGMENT-SWIZZLED weights, 36 row-groups x 8 ks chunks of 512:
//       element (n,k) at ((n>>4)*8 + (k>>5))*512 + ((k>>3)&3)*128
//       + (n&15)*8 + (k&7).  n = concat col {0..31 Wf, 32..63 Wg*log2e,
//       64..319 Wh, 320..575 Wv}.
//   | lpart f32 [S][16384]  (UN-normalized split row-sums l_s)
//   | obf bf16 [S][1<<22]   RAW split outputs, same fragment swizzle
//
// MEASURED LEDGER: total 199.5 -> 158.3 over 12 rounds. attn8 = 52.6us
// (128-row q-tiles, S=4, all-operand fragment swizzle, raw epilogue).
// wT swizzle R12: -14.6us (proj/final scatter fixed). R11 calibration:
// per-ITERATION harness overhead ~85-90us (1-kernel run: 376 total vs 289
// dispatch) -> addressable kernel time now ~73us. proj~11 final~7 prep~2
// are near floor. THIS ROUND: isolated T5 test — s_setprio(1) around
// attn8's PV MFMA clusters only (m191: +4-7% attn; attn9 bundled it with
// harmful changes, this is the clean A/B on the proven base).

typedef unsigned short u16;
typedef __attribute__((ext_vector_type(8))) short  bf16x8;
typedef __attribute__((ext_vector_type(4))) float  f32x4;

__device__ inline u16 f2bf(float x) {
    unsigned u = __float_as_uint(x);
    unsigned r = (u + 0x7fffu + ((u >> 16) & 1u)) >> 16;
    return (u16)r;
}

__device__ inline float bf2f(short s) {
    return __uint_as_float(((unsigned)(u16)s) << 16);
}

__device__ inline bf16x8 cvt8(float4 a, float4 b) {
    bf16x8 r;
    r[0] = (short)f2bf(a.x); r[1] = (short)f2bf(a.y);
    r[2] = (short)f2bf(a.z); r[3] = (short)f2bf(a.w);
    r[4] = (short)f2bf(b.x); r[5] = (short)f2bf(b.y);
    r[6] = (short)f2bf(b.z); r[7] = (short)f2bf(b.w);
    return r;
}

#define ASYNC_CP16(gp, lp)                                                     \
    __builtin_amdgcn_global_load_lds(                                          \
        (const __attribute__((address_space(1))) void*)(gp),                   \
        (__attribute__((address_space(3))) void*)(lp), 16, 0, 0)

#define LOG2E 1.4426950408889634f

// V-fragment address: chunk(b,cg,kc)*512 + quad*128 + l16*8
__device__ inline size_t vfrag_off(int b, int cg, int kc, int quad, int l16) {
    return ((((size_t)b * 16 + cg) * 128 + kc) << 9) + (quad << 7) + (l16 << 3);
}

// wT-fragment address: row-group n16 (0..35), k-chunk ks (0..7)
__device__ inline size_t wfrag_off(int n16, int ks, int quad, int l16) {
    return (((size_t)n16 * 8 + ks) << 9) + (quad << 7) + (l16 << 3);
}

// ---------------------------------------------------------------------------
// prep_w3: pack weights into FRAGMENT-SWIZZLED wT. 18 blocks x 32 n-rows.
// ---------------------------------------------------------------------------
__global__ __launch_bounds__(256) void prep_w3(
    const float* __restrict__ Wf, const float* __restrict__ Wg,
    const float* __restrict__ Wh, const float* __restrict__ Wv,
    u16* __restrict__ wT)
{
    __shared__ float ldsw[256 * 33];

    const int bid = blockIdx.x;
    const int t   = threadIdx.x;

    const float* src; int cs, c0, nbase; float scale = 1.f;
    if (bid == 0)      { src = Wf; cs = 32;  c0 = 0;              nbase = 0; }
    else if (bid == 1) { src = Wg; cs = 32;  c0 = 0;              nbase = 32;  scale = LOG2E; }
    else if (bid < 10) { src = Wh; cs = 256; c0 = (bid - 2) * 32; nbase = 64  + (bid - 2) * 32; }
    else               { src = Wv; cs = 256; c0 = (bid - 10) * 32; nbase = 320 + (bid - 10) * 32; }

#pragma unroll
    for (int i = 0; i < 32; ++i) {
        int idx = i * 256 + t;
        int k = idx >> 5, n = idx & 31;
        ldsw[k * 33 + n] = src[(size_t)k * cs + c0 + n];
    }
    __syncthreads();

#pragma unroll
    for (int i = 0; i < 4; ++i) {
        int w16   = i * 256 + t;          // 0..1023
        int l16v  = w16 & 15;
        int quadv = (w16 >> 4) & 3;
        int ksv   = (w16 >> 6) & 7;
        int n16l  = w16 >> 9;             // 0..1
        int n     = n16l * 16 + l16v;     // 0..31 local
        int k0    = ksv * 32 + quadv * 8;
        bf16x8 vv;
#pragma unroll
        for (int j = 0; j < 8; ++j)
            vv[j] = (short)f2bf(ldsw[(k0 + j) * 33 + n] * scale);
        *reinterpret_cast<bf16x8*>(
            wT + wfrag_off((nbase >> 4) + n16l, ksv, quadv, l16v)) = vv;
    }
}

// ---------------------------------------------------------------------------
// proj: Y[16384,320] = x @ [Wf|Wg|Wh] + bias, bf16 MFMA. 16 rows/block
// (grid 1024). bfrag reads 1KB contiguous/wave from swizzled wT.
// ---------------------------------------------------------------------------
__global__ __launch_bounds__(256) void proj_mfma3(
    const float* __restrict__ x, const u16* __restrict__ wT,
    const float* __restrict__ bfv, const float* __restrict__ bgv,
    const float* __restrict__ bhv,
    u16* __restrict__ fg, u16* __restrict__ hmt)
{
    __shared__ float xl[16 * 268];   // 16 rows, stride 268 (1072 B)

    const int t    = threadIdx.x;
    const int w    = t >> 6;
    const int lane = t & 63;
    const int quad = lane >> 4;
    const int l16  = lane & 15;
    const int m0   = blockIdx.x * 16;
    const int wb   = w * 80;

#pragma unroll
    for (int i = 0; i < 4; ++i) {
        int idx = i * 256 + t;
        int row = idx >> 6;
        int c4  = (idx & 63) << 2;
        float4 v = *reinterpret_cast<const float4*>(
            x + (size_t)(m0 + row) * 256 + c4);
        *reinterpret_cast<float4*>(&xl[row * 268 + c4]) = v;
    }
    __syncthreads();

    f32x4 acc[5];
#pragma unroll
    for (int nt = 0; nt < 5; ++nt)
#pragma unroll
        for (int r = 0; r < 4; ++r) acc[nt][r] = 0.f;

#pragma unroll 2
    for (int ks = 0; ks < 8; ++ks) {
        const float* xp = &xl[l16 * 268 + ks * 32 + quad * 8];
        float4 a0 = *reinterpret_cast<const float4*>(xp);
        float4 a1 = *reinterpret_cast<const float4*>(xp + 4);
        bf16x8 afrag = cvt8(a0, a1);
#pragma unroll
        for (int nt = 0; nt < 5; ++nt) {
            bf16x8 bfrag = *reinterpret_cast<const bf16x8*>(
                wT + wfrag_off(w * 5 + nt, ks, quad, l16));
            acc[nt] = __builtin_amdgcn_mfma_f32_16x16x32_bf16(
                afrag, bfrag, acc[nt], 0, 0, 0);
        }
    }

    const int bb   = m0 >> 12;
    const int npix = m0 & 4095;
#pragma unroll
    for (int nt = 0; nt < 5; ++nt) {
        int col = wb + nt * 16 + l16;
        if (col < 64) {
            float bias = (col < 32) ? bfv[col] : bgv[col - 32] * LOG2E;
            int row = m0 + quad * 4;
#pragma unroll
            for (int r = 0; r < 4; ++r)
                fg[(size_t)(row + r) * 64 + col] = f2bf(acc[nt][r] + bias);
        } else {
            int c = col - 64;
            float bias = bhv[c];
            int n0 = npix + quad * 4;
            ushort4 hv;
            hv.x = f2bf(acc[nt][0] + bias);
            hv.y = f2bf(acc[nt][1] + bias);
            hv.z = f2bf(acc[nt][2] + bias);
            hv.w = f2bf(acc[nt][3] + bias);
            size_t off = ((((size_t)bb * 16 + (c >> 4)) * 128 + (n0 >> 5))
                          << 9) + (((n0 >> 3) & 3) << 7) + ((c & 15) << 3) +
                         (n0 & 7);
            *reinterpret_cast<ushort4*>(hmt + off) = hv;
        }
    }
}

// ---------------------------------------------------------------------------
// attn5 (FALLBACK for ksl<=1): 64-row tiles. Writes RAW oacc + lpart.
// ---------------------------------------------------------------------------
__global__ __launch_bounds__(256) void attn5(
    const u16* __restrict__ fg, const u16* __restrict__ hmt,
    u16* __restrict__ obf, float* __restrict__ lpart, int ksl)
{
    __shared__ u16 fl[2][4096];
    __shared__ u16 pl[8192];
    const int t    = threadIdx.x;
    const int w    = t >> 6;
    const int lane = t & 63;
    const int quad = lane >> 4;
    const int l16  = lane & 15;
    int b, qt, ks;
    if (ksl == 1) {
        const int u   = blockIdx.x;
        const int xcd = u & 7;
        b = xcd >> 1;
        const int v = ((u >> 3) << 1) | (xcd & 1);
        qt = v >> 1;
        ks = v & 1;
    } else {
        ks = 0;
        qt = blockIdx.x & 63;
        b  = blockIdx.x >> 6;
    }
    const int nkt = 32 >> ksl;
    const int kt0 = ks * nkt;
    const size_t fg_base = (size_t)b * 4096 * 64;
    const bf16x8 gfrag = *reinterpret_cast<const bf16x8*>(
        fg + fg_base + (size_t)(qt * 64 + w * 16 + l16) * 64 + 32 + quad * 8);
    f32x4 oacc[4][4];
#pragma unroll
    for (int mt = 0; mt < 4; ++mt)
#pragma unroll
        for (int nt = 0; nt < 4; ++nt)
#pragma unroll
            for (int r = 0; r < 4; ++r) oacc[mt][nt][r] = 0.f;
    float lsum[4] = {0.f, 0.f, 0.f, 0.f};
    const f32x4 zero4 = {0.f, 0.f, 0.f, 0.f};
    {
        const u16* gp = fg + fg_base +
            (size_t)(kt0 * 128 + (2 * w) * 16 + l16) * 64 + quad * 8;
        ASYNC_CP16(gp, &fl[0][(2 * w) * 512]);
        ASYNC_CP16(gp + 16 * 64, &fl[0][(2 * w + 1) * 512]);
    }
    for (int it = 0; it < nkt; ++it) {
        const int kt  = kt0 + it;
        const int buf = it & 1;
        __syncthreads();
        bf16x8 vbr[4][4];
#pragma unroll
        for (int nt = 0; nt < 4; ++nt)
#pragma unroll
            for (int kh = 0; kh < 4; ++kh)
                vbr[nt][kh] = *reinterpret_cast<const bf16x8*>(
                    hmt + vfrag_off(b, w * 4 + nt, kt * 4 + kh, quad, l16));
        if (it + 1 < nkt) {
            const u16* gp = fg + fg_base +
                (size_t)((kt + 1) * 128 + (2 * w) * 16 + l16) * 64 + quad * 8;
            ASYNC_CP16(gp, &fl[buf ^ 1][(2 * w) * 512]);
            ASYNC_CP16(gp + 16 * 64, &fl[buf ^ 1][(2 * w + 1) * 512]);
        }
        f32x4 sacc[8];
#pragma unroll
        for (int ct = 0; ct < 8; ++ct) {
            bf16x8 fb = *reinterpret_cast<const bf16x8*>(
                &fl[buf][ct * 512 + quad * 128 + l16 * 8]);
            sacc[ct] = __builtin_amdgcn_mfma_f32_16x16x32_bf16(
                gfrag, fb, zero4, 0, 0, 0);
        }
#pragma unroll
        for (int ct = 0; ct < 8; ++ct) {
#pragma unroll
            for (int r = 0; r < 4; ++r) {
                float p = __builtin_amdgcn_exp2f(sacc[ct][r]);
                lsum[r] += p;
                int row = w * 16 + quad * 4 + r;
                int key = ct * 16 + l16;
                pl[(key >> 3) * 512 + row * 8 + (key & 7)] = f2bf(p);
            }
        }
        __syncthreads();
#pragma unroll
        for (int kh = 0; kh < 4; ++kh) {
            bf16x8 pa[4];
#pragma unroll
            for (int mt = 0; mt < 4; ++mt)
                pa[mt] = *reinterpret_cast<const bf16x8*>(
                    &pl[(kh * 4 + quad) * 512 + (mt * 16 + l16) * 8]);
#pragma unroll
            for (int nt = 0; nt < 4; ++nt)
#pragma unroll
                for (int mt = 0; mt < 4; ++mt)
                    oacc[mt][nt] = __builtin_amdgcn_mfma_f32_16x16x32_bf16(
                        pa[mt], vbr[nt][kh], oacc[mt][nt], 0, 0, 0);
        }
    }
#pragma unroll
    for (int r = 0; r < 4; ++r) {
        float s = lsum[r];
        s += __shfl_xor(s, 1);
        s += __shfl_xor(s, 2);
        s += __shfl_xor(s, 4);
        s += __shfl_xor(s, 8);
        lsum[r] = s;
    }
    if (l16 == 0) {
#pragma unroll
        for (int r = 0; r < 4; ++r)
            lpart[((size_t)ks << 14) + b * 4096 + qt * 64 + w * 16 +
                  quad * 4 + r] = lsum[r];
    }
#pragma unroll
    for (int mt = 0; mt < 4; ++mt) {
        const int row16 = b * 256 + qt * 4 + mt;
#pragma unroll
        for (int nt = 0; nt < 4; ++nt) {
            int ksc = w * 2 + (nt >> 1);
            int qc  = (nt & 1) * 2 + (l16 >> 3);
            u16* op = obf + ((size_t)ks << 22) +
                (((size_t)row16 * 8 + ksc) << 9) + (qc << 7) + (l16 & 7);
#pragma unroll
            for (int r = 0; r < 4; ++r)
                op[(quad * 4 + r) * 8] = f2bf(oacc[mt][nt][r]);
        }
    }
}

// ---------------------------------------------------------------------------
// attn10 = attn8 (proven 52.6us) + s_setprio(1/0) around PV MFMA clusters
// ONLY (isolated T5 test; m191 measured +4-7% on attn). Everything else
// byte-identical: 128-row q-tiles, S=4, swizzled hmt V, raw epilogue.
// ---------------------------------------------------------------------------
__global__ __launch_bounds__(256, 2) void attn10(
    const u16* __restrict__ fg, const u16* __restrict__ hmt,
    u16* __restrict__ obf, float* __restrict__ lpart, int ksl)
{
    __shared__ u16 fl[2][4096];
    __shared__ u16 pl[16 * 1024];
    const int t    = threadIdx.x;
    const int w    = t >> 6;
    const int lane = t & 63;
    const int quad = lane >> 4;
    const int l16  = lane & 15;
    const int u   = blockIdx.x;
    const int xcd = u & 7;
    const int b   = xcd >> 1;
    const int v   = ((u >> 3) << 1) | (xcd & 1);
    const int qt  = v >> ksl;
    const int ks  = v & ((1 << ksl) - 1);
    const int nkt = 32 >> ksl;
    const int kt0 = ks * nkt;
    const size_t fg_base = (size_t)b * 4096 * 64;
    bf16x8 gfrag[2];
#pragma unroll
    for (int h2 = 0; h2 < 2; ++h2)
        gfrag[h2] = *reinterpret_cast<const bf16x8*>(
            fg + fg_base +
            (size_t)(qt * 128 + w * 32 + h2 * 16 + l16) * 64 + 32 + quad * 8);
    f32x4 oacc[8][4];
#pragma unroll
    for (int mt = 0; mt < 8; ++mt)
#pragma unroll
        for (int nt = 0; nt < 4; ++nt)
#pragma unroll
            for (int r = 0; r < 4; ++r) oacc[mt][nt][r] = 0.f;
    float lsum[2][4] = {{0.f, 0.f, 0.f, 0.f}, {0.f, 0.f, 0.f, 0.f}};
    const f32x4 zero4 = {0.f, 0.f, 0.f, 0.f};
    {
        const u16* gp = fg + fg_base +
            (size_t)(kt0 * 128 + (2 * w) * 16 + l16) * 64 + quad * 8;
        ASYNC_CP16(gp, &fl[0][(2 * w) * 512]);
        ASYNC_CP16(gp + 16 * 64, &fl[0][(2 * w + 1) * 512]);
    }
    for (int it = 0; it < nkt; ++it) {
        const int kt  = kt0 + it;
        const int buf = it & 1;
        __syncthreads();   // B1
        if (it + 1 < nkt) {
            const u16* gp = fg + fg_base +
                (size_t)((kt + 1) * 128 + (2 * w) * 16 + l16) * 64 + quad * 8;
            ASYNC_CP16(gp, &fl[buf ^ 1][(2 * w) * 512]);
            ASYNC_CP16(gp + 16 * 64, &fl[buf ^ 1][(2 * w + 1) * 512]);
        }
        // QK row-half 0
        {
            f32x4 sacc[8];
#pragma unroll
            for (int ct = 0; ct < 8; ++ct) {
                bf16x8 fb = *reinterpret_cast<const bf16x8*>(
                    &fl[buf][ct * 512 + quad * 128 + l16 * 8]);
                sacc[ct] = __builtin_amdgcn_mfma_f32_16x16x32_bf16(
                    gfrag[0], fb, zero4, 0, 0, 0);
            }
#pragma unroll
            for (int ct = 0; ct < 8; ++ct) {
#pragma unroll
                for (int r = 0; r < 4; ++r) {
                    float p = __builtin_amdgcn_exp2f(sacc[ct][r]);
                    lsum[0][r] += p;
                    int row = w * 32 + quad * 4 + r;
                    int key = ct * 16 + l16;
                    pl[(key >> 3) * 1024 + row * 8 + (key & 7)] = f2bf(p);
                }
            }
        }
        // V kh-pair A
        bf16x8 va[4][2];
#pragma unroll
        for (int nt = 0; nt < 4; ++nt)
#pragma unroll
            for (int j = 0; j < 2; ++j)
                va[nt][j] = *reinterpret_cast<const bf16x8*>(
                    hmt + vfrag_off(b, w * 4 + nt, kt * 4 + j, quad, l16));
        // QK row-half 1
        {
            f32x4 sacc[8];
#pragma unroll
            for (int ct = 0; ct < 8; ++ct) {
                bf16x8 fb = *reinterpret_cast<const bf16x8*>(
                    &fl[buf][ct * 512 + quad * 128 + l16 * 8]);
                sacc[ct] = __builtin_amdgcn_mfma_f32_16x16x32_bf16(
                    gfrag[1], fb, zero4, 0, 0, 0);
            }
#pragma unroll
            for (int ct = 0; ct < 8; ++ct) {
#pragma unroll
                for (int r = 0; r < 4; ++r) {
                    float p = __builtin_amdgcn_exp2f(sacc[ct][r]);
                    lsum[1][r] += p;
                    int row = w * 32 + 16 + quad * 4 + r;
                    int key = ct * 16 + l16;
                    pl[(key >> 3) * 1024 + row * 8 + (key & 7)] = f2bf(p);
                }
            }
        }
        __syncthreads();   // B2
        // PV kh-pair A (setprio: T5 — favor MFMA waves during arbitration)
        __builtin_amdgcn_s_setprio(1);
#pragma unroll
        for (int kh = 0; kh < 2; ++kh) {
#pragma unroll
            for (int mh = 0; mh < 2; ++mh) {
                bf16x8 pa[4];
#pragma unroll
                for (int m = 0; m < 4; ++m)
                    pa[m] = *reinterpret_cast<const bf16x8*>(
                        &pl[(kh * 4 + quad) * 1024 +
                            ((mh * 4 + m) * 16 + l16) * 8]);
#pragma unroll
                for (int nt = 0; nt < 4; ++nt)
#pragma unroll
                    for (int m = 0; m < 4; ++m)
                        oacc[mh * 4 + m][nt] =
                            __builtin_amdgcn_mfma_f32_16x16x32_bf16(
                                pa[m], va[nt][kh], oacc[mh * 4 + m][nt],
                                0, 0, 0);
            }
        }
        __builtin_amdgcn_s_setprio(0);
        // V kh-pair B
        bf16x8 vb[4][2];
#pragma unroll
        for (int nt = 0; nt < 4; ++nt)
#pragma unroll
            for (int j = 0; j < 2; ++j)
                vb[nt][j] = *reinterpret_cast<const bf16x8*>(
                    hmt + vfrag_off(b, w * 4 + nt, kt * 4 + 2 + j, quad, l16));
        __builtin_amdgcn_s_setprio(1);
#pragma unroll
        for (int kh = 2; kh < 4; ++kh) {
#pragma unroll
            for (int mh = 0; mh < 2; ++mh) {
                bf16x8 pa[4];
#pragma unroll
                for (int m = 0; m < 4; ++m)
                    pa[m] = *reinterpret_cast<const bf16x8*>(
                        &pl[(kh * 4 + quad) * 1024 +
                            ((mh * 4 + m) * 16 + l16) * 8]);
#pragma unroll
                for (int nt = 0; nt < 4; ++nt)
#pragma unroll
                    for (int m = 0; m < 4; ++m)
                        oacc[mh * 4 + m][nt] =
                            __builtin_amdgcn_mfma_f32_16x16x32_bf16(
                                pa[m], vb[nt][kh - 2], oacc[mh * 4 + m][nt],
                                0, 0, 0);
            }
        }
        __builtin_amdgcn_s_setprio(0);
    }
#pragma unroll
    for (int h2 = 0; h2 < 2; ++h2) {
#pragma unroll
        for (int r = 0; r < 4; ++r) {
            float s = lsum[h2][r];
            s += __shfl_xor(s, 1);
            s += __shfl_xor(s, 2);
            s += __shfl_xor(s, 4);
            s += __shfl_xor(s, 8);
            lsum[h2][r] = s;
        }
    }
    if (l16 == 0) {
#pragma unroll
        for (int h2 = 0; h2 < 2; ++h2)
#pragma unroll
            for (int r = 0; r < 4; ++r) {
                int row = w * 32 + h2 * 16 + quad * 4 + r;
                lpart[((size_t)ks << 14) + b * 4096 + qt * 128 + row] =
                    lsum[h2][r];
            }
    }
#pragma unroll
    for (int mt = 0; mt < 8; ++mt) {
        const int row16 = b * 256 + qt * 8 + mt;
#pragma unroll
        for (int nt = 0; nt < 4; ++nt) {
            int ksc = w * 2 + (nt >> 1);
            int qc  = (nt & 1) * 2 + (l16 >> 3);
            u16* op = obf + ((size_t)ks << 22) +
                (((size_t)row16 * 8 + ksc) << 9) + (qc << 7) + (l16 & 7);
#pragma unroll
            for (int r = 0; r < 4; ++r)
                op[(quad * 4 + r) * 8] = f2bf(oacc[mt][nt][r]);
        }
    }
}

// ---------------------------------------------------------------------------
// final v9: out = x + (Sigma_s O_raw_s) @ Wv * inv[row] + bv.
// obf LDS-staged (coalesced); plain-sum combine; single MFMA set; bfrag
// 1KB contiguous/wave from swizzled wT (row-groups 20..35).
// ---------------------------------------------------------------------------
__global__ __launch_bounds__(256) void final_mfma9(
    const u16* __restrict__ obf, const float* __restrict__ lpart, int S,
    const u16* __restrict__ wT, const float* __restrict__ bvv,
    const float* __restrict__ x, float* __restrict__ out)
{
    __shared__ u16 ol[16384];
    __shared__ float linv[16];
    const int t    = threadIdx.x;
    const int w    = t >> 6;
    const int lane = t & 63;
    const int quad = lane >> 4;
    const int l16  = lane & 15;
    const int m0   = blockIdx.x * 16;
    const int wb   = w * 64;

    const int ni = S * 2;
    for (int i = 0; i < ni; ++i) {
        int gi = w * ni + i;
        int s  = gi >> 3;
        int ks = gi & 7;
        const u16* gp = obf + ((size_t)s << 22) +
            (((size_t)(m0 >> 4) * 8 + ks) << 9) + lane * 8;
        ASYNC_CP16(gp, &ol[gi * 512]);
    }
    if (t < 16) {
        float tot = 0.f;
#pragma unroll
        for (int s = 0; s < 4; ++s)
            if (s < S) tot += lpart[((size_t)s << 14) + m0 + t];
        linv[t] = 1.f / tot;
    }
    __syncthreads();

    f32x4 acc[4];
#pragma unroll
    for (int nt = 0; nt < 4; ++nt)
#pragma unroll
        for (int r = 0; r < 4; ++r) acc[nt][r] = 0.f;

#pragma unroll 2
    for (int ks = 0; ks < 8; ++ks) {
        bf16x8 afrag;
        {
            bf16x8 v0 = *reinterpret_cast<const bf16x8*>(
                &ol[ks * 512 + lane * 8]);
            if (S == 1) {
                afrag = v0;
            } else {
                float tacc[8];
#pragma unroll
                for (int j = 0; j < 8; ++j) tacc[j] = bf2f(v0[j]);
#pragma unroll
                for (int s = 1; s < 4; ++s) {
                    if (s < S) {
                        bf16x8 vs = *reinterpret_cast<const bf16x8*>(
                            &ol[(s * 8 + ks) * 512 + lane * 8]);
#pragma unroll
                        for (int j = 0; j < 8; ++j) tacc[j] += bf2f(vs[j]);
                    }
                }
#pragma unroll
                for (int j = 0; j < 8; ++j) afrag[j] = (short)f2bf(tacc[j]);
            }
        }
#pragma unroll
        for (int nt = 0; nt < 4; ++nt) {
            bf16x8 bfrag = *reinterpret_cast<const bf16x8*>(
                wT + wfrag_off(20 + w * 4 + nt, ks, quad, l16));
            acc[nt] = __builtin_amdgcn_mfma_f32_16x16x32_bf16(
                afrag, bfrag, acc[nt], 0, 0, 0);
        }
    }

#pragma unroll
    for (int nt = 0; nt < 4; ++nt) {
        int col = wb + nt * 16 + l16;
        float bias = bvv[col];
        int row = m0 + quad * 4;
#pragma unroll
        for (int r = 0; r < 4; ++r) {
            size_t off = (size_t)(row + r) * 256 + col;
            out[off] = acc[nt][r] * linv[quad * 4 + r] + bias + x[off];
        }
    }
}

// ---------------------------------------------------------------------------
extern "C" void kernel_launch(void* const* d_in, const int* in_sizes, int n_in,
                              void* d_out, int out_size, void* d_ws, size_t ws_size,
                              hipStream_t stream)
{
    const float* x  = (const float*)d_in[0];
    const float* Wf = (const float*)d_in[1];
    const float* bf = (const float*)d_in[2];
    const float* Wg = (const float*)d_in[3];
    const float* bg = (const float*)d_in[4];
    const float* Wh = (const float*)d_in[5];
    const float* bh = (const float*)d_in[6];
    const float* Wv = (const float*)d_in[7];
    const float* bv = (const float*)d_in[8];
    float* out = (float*)d_out;

    const int M = 16384;

    const size_t base_b = (size_t)M * 64 * 2 + (size_t)4 * 256 * 4096 * 2 +
                          (size_t)576 * 256 * 2;
    const size_t per_s  = (size_t)M * 4 + (size_t)M * 256 * 2;
    int ksl = 0;
    if (ws_size >= base_b + 4 * per_s)      ksl = 2;
    else if (ws_size >= base_b + 2 * per_s) ksl = 1;
    const int S = 1 << ksl;

    u16*   fgbuf = (u16*)d_ws;
    u16*   hmt   = fgbuf + (size_t)M * 64;
    u16*   wT    = hmt + (size_t)4 * 256 * 4096;
    float* lpart = (float*)(wT + (size_t)576 * 256);
    u16*   obf   = (u16*)(lpart + (size_t)S * M);

    dim3 blk(256);

    prep_w3<<<dim3(18), blk, 0, stream>>>(Wf, Wg, Wh, Wv, wT);
    proj_mfma3<<<dim3(M / 16), blk, 0, stream>>>(x, wT, bf, bg, bh, fgbuf, hmt);
    if (ksl == 2)
        attn10<<<dim3(512), blk, 0, stream>>>(fgbuf, hmt, obf, lpart, ksl);
    else
        attn5<<<dim3(256 * S), blk, 0, stream>>>(fgbuf, hmt, obf, lpart, ksl);
    final_mfma9<<<dim3(M / 16), blk, 0, stream>>>(
        obf, lpart, S, wT, bv, x, out);
}

// Round 14
// 158.206 us; speedup vs baseline: 1.0074x; 1.0074x over previous
//
#include <hip/hip_runtime.h>
#include <math.h>

// B=4, H=W=64, C=256, Ck=32, N=4096, M=B*N=16384
// ws: fg bf16 [16384][64] (f=cols0..31, g=cols32..63, g pre-scaled by log2e)
//   | hmt bf16 FRAGMENT-SWIZZLED V: chunk(b, cg=c>>4, kc=key>>5) of 512 u16;
//       element (c,key) at chunk*512 + ((key>>3)&3)*128 + (c&15)*8 + (key&7)
//   | wT bf16 FRAGMENT-SWIZZLED weights, 36 row-groups x 8 ks chunks of 512:
//       element (n,k) at ((n>>4)*8 + (k>>5))*512 + ((k>>3)&3)*128
//       + (n&15)*8 + (k&7).  n = concat col {0..31 Wf, 32..63 Wg*log2e,
//       64..319 Wh, 320..575 Wv}.
//   | lpart f32 [S][16384]  (UN-normalized split row-sums l_s)
//   | obf bf16 [S][1<<22]   RAW split outputs, same fragment swizzle
//
// FINAL CONFIGURATION (R12, best measured total 158.3us):
//   attn8 52.6us | proj ~11 | final ~7 | prep ~2 | harness ~85-90 fixed.
// Ledger 199.5 -> 158.3 over 13 rounds. Verified wins: 128-row q-tiles+S=4
// (V-traffic halved, -20.5), hmt fragment swizzle (-4.4), wT fragment
// swizzle (-14.6), raw epilogue (-1.3), coalesced prep. Verified nulls/
// regressions: S=4-at-64row (+15%), fewer barriers (0), 32-row occupancy
// (+85%), QK-fusion+staged-vb (+23%), MFMA-linearity final (+4us), coop
// fusion (+120%), setprio (R13: null). attn8 plateau = 28% MfmaUtil / 27%
// VALU / 9.5% HBM: serialization-bound; the remaining gap needs the full
// co-designed 8-phase+in-reg-softmax pipeline (partials measured regressive).

typedef unsigned short u16;
typedef __attribute__((ext_vector_type(8))) short  bf16x8;
typedef __attribute__((ext_vector_type(4))) float  f32x4;

__device__ inline u16 f2bf(float x) {
    unsigned u = __float_as_uint(x);
    unsigned r = (u + 0x7fffu + ((u >> 16) & 1u)) >> 16;
    return (u16)r;
}

__device__ inline float bf2f(short s) {
    return __uint_as_float(((unsigned)(u16)s) << 16);
}

__device__ inline bf16x8 cvt8(float4 a, float4 b) {
    bf16x8 r;
    r[0] = (short)f2bf(a.x); r[1] = (short)f2bf(a.y);
    r[2] = (short)f2bf(a.z); r[3] = (short)f2bf(a.w);
    r[4] = (short)f2bf(b.x); r[5] = (short)f2bf(b.y);
    r[6] = (short)f2bf(b.z); r[7] = (short)f2bf(b.w);
    return r;
}

#define ASYNC_CP16(gp, lp)                                                     \
    __builtin_amdgcn_global_load_lds(                                          \
        (const __attribute__((address_space(1))) void*)(gp),                   \
        (__attribute__((address_space(3))) void*)(lp), 16, 0, 0)

#define LOG2E 1.4426950408889634f

// V-fragment address: chunk(b,cg,kc)*512 + quad*128 + l16*8
__device__ inline size_t vfrag_off(int b, int cg, int kc, int quad, int l16) {
    return ((((size_t)b * 16 + cg) * 128 + kc) << 9) + (quad << 7) + (l16 << 3);
}

// wT-fragment address: row-group n16 (0..35), k-chunk ks (0..7)
__device__ inline size_t wfrag_off(int n16, int ks, int quad, int l16) {
    return (((size_t)n16 * 8 + ks) << 9) + (quad << 7) + (l16 << 3);
}

// ---------------------------------------------------------------------------
// prep_w3: pack weights into FRAGMENT-SWIZZLED wT. 18 blocks x 32 n-rows.
// ---------------------------------------------------------------------------
__global__ __launch_bounds__(256) void prep_w3(
    const float* __restrict__ Wf, const float* __restrict__ Wg,
    const float* __restrict__ Wh, const float* __restrict__ Wv,
    u16* __restrict__ wT)
{
    __shared__ float ldsw[256 * 33];

    const int bid = blockIdx.x;
    const int t   = threadIdx.x;

    const float* src; int cs, c0, nbase; float scale = 1.f;
    if (bid == 0)      { src = Wf; cs = 32;  c0 = 0;              nbase = 0; }
    else if (bid == 1) { src = Wg; cs = 32;  c0 = 0;              nbase = 32;  scale = LOG2E; }
    else if (bid < 10) { src = Wh; cs = 256; c0 = (bid - 2) * 32; nbase = 64  + (bid - 2) * 32; }
    else               { src = Wv; cs = 256; c0 = (bid - 10) * 32; nbase = 320 + (bid - 10) * 32; }

#pragma unroll
    for (int i = 0; i < 32; ++i) {
        int idx = i * 256 + t;
        int k = idx >> 5, n = idx & 31;
        ldsw[k * 33 + n] = src[(size_t)k * cs + c0 + n];
    }
    __syncthreads();

#pragma unroll
    for (int i = 0; i < 4; ++i) {
        int w16   = i * 256 + t;          // 0..1023
        int l16v  = w16 & 15;
        int quadv = (w16 >> 4) & 3;
        int ksv   = (w16 >> 6) & 7;
        int n16l  = w16 >> 9;             // 0..1
        int n     = n16l * 16 + l16v;     // 0..31 local
        int k0    = ksv * 32 + quadv * 8;
        bf16x8 vv;
#pragma unroll
        for (int j = 0; j < 8; ++j)
            vv[j] = (short)f2bf(ldsw[(k0 + j) * 33 + n] * scale);
        *reinterpret_cast<bf16x8*>(
            wT + wfrag_off((nbase >> 4) + n16l, ksv, quadv, l16v)) = vv;
    }
}

// ---------------------------------------------------------------------------
// proj: Y[16384,320] = x @ [Wf|Wg|Wh] + bias, bf16 MFMA. 16 rows/block
// (grid 1024). bfrag reads 1KB contiguous/wave from swizzled wT.
// ---------------------------------------------------------------------------
__global__ __launch_bounds__(256) void proj_mfma3(
    const float* __restrict__ x, const u16* __restrict__ wT,
    const float* __restrict__ bfv, const float* __restrict__ bgv,
    const float* __restrict__ bhv,
    u16* __restrict__ fg, u16* __restrict__ hmt)
{
    __shared__ float xl[16 * 268];   // 16 rows, stride 268 (1072 B)

    const int t    = threadIdx.x;
    const int w    = t >> 6;
    const int lane = t & 63;
    const int quad = lane >> 4;
    const int l16  = lane & 15;
    const int m0   = blockIdx.x * 16;
    const int wb   = w * 80;

#pragma unroll
    for (int i = 0; i < 4; ++i) {
        int idx = i * 256 + t;
        int row = idx >> 6;
        int c4  = (idx & 63) << 2;
        float4 v = *reinterpret_cast<const float4*>(
            x + (size_t)(m0 + row) * 256 + c4);
        *reinterpret_cast<float4*>(&xl[row * 268 + c4]) = v;
    }
    __syncthreads();

    f32x4 acc[5];
#pragma unroll
    for (int nt = 0; nt < 5; ++nt)
#pragma unroll
        for (int r = 0; r < 4; ++r) acc[nt][r] = 0.f;

#pragma unroll 2
    for (int ks = 0; ks < 8; ++ks) {
        const float* xp = &xl[l16 * 268 + ks * 32 + quad * 8];
        float4 a0 = *reinterpret_cast<const float4*>(xp);
        float4 a1 = *reinterpret_cast<const float4*>(xp + 4);
        bf16x8 afrag = cvt8(a0, a1);
#pragma unroll
        for (int nt = 0; nt < 5; ++nt) {
            bf16x8 bfrag = *reinterpret_cast<const bf16x8*>(
                wT + wfrag_off(w * 5 + nt, ks, quad, l16));
            acc[nt] = __builtin_amdgcn_mfma_f32_16x16x32_bf16(
                afrag, bfrag, acc[nt], 0, 0, 0);
        }
    }

    const int bb   = m0 >> 12;
    const int npix = m0 & 4095;
#pragma unroll
    for (int nt = 0; nt < 5; ++nt) {
        int col = wb + nt * 16 + l16;
        if (col < 64) {
            float bias = (col < 32) ? bfv[col] : bgv[col - 32] * LOG2E;
            int row = m0 + quad * 4;
#pragma unroll
            for (int r = 0; r < 4; ++r)
                fg[(size_t)(row + r) * 64 + col] = f2bf(acc[nt][r] + bias);
        } else {
            int c = col - 64;
            float bias = bhv[c];
            int n0 = npix + quad * 4;
            ushort4 hv;
            hv.x = f2bf(acc[nt][0] + bias);
            hv.y = f2bf(acc[nt][1] + bias);
            hv.z = f2bf(acc[nt][2] + bias);
            hv.w = f2bf(acc[nt][3] + bias);
            size_t off = ((((size_t)bb * 16 + (c >> 4)) * 128 + (n0 >> 5))
                          << 9) + (((n0 >> 3) & 3) << 7) + ((c & 15) << 3) +
                         (n0 & 7);
            *reinterpret_cast<ushort4*>(hmt + off) = hv;
        }
    }
}

// ---------------------------------------------------------------------------
// attn5 (FALLBACK for ksl<=1): 64-row tiles. Writes RAW oacc + lpart.
// ---------------------------------------------------------------------------
__global__ __launch_bounds__(256) void attn5(
    const u16* __restrict__ fg, const u16* __restrict__ hmt,
    u16* __restrict__ obf, float* __restrict__ lpart, int ksl)
{
    __shared__ u16 fl[2][4096];
    __shared__ u16 pl[8192];
    const int t    = threadIdx.x;
    const int w    = t >> 6;
    const int lane = t & 63;
    const int quad = lane >> 4;
    const int l16  = lane & 15;
    int b, qt, ks;
    if (ksl == 1) {
        const int u   = blockIdx.x;
        const int xcd = u & 7;
        b = xcd >> 1;
        const int v = ((u >> 3) << 1) | (xcd & 1);
        qt = v >> 1;
        ks = v & 1;
    } else {
        ks = 0;
        qt = blockIdx.x & 63;
        b  = blockIdx.x >> 6;
    }
    const int nkt = 32 >> ksl;
    const int kt0 = ks * nkt;
    const size_t fg_base = (size_t)b * 4096 * 64;
    const bf16x8 gfrag = *reinterpret_cast<const bf16x8*>(
        fg + fg_base + (size_t)(qt * 64 + w * 16 + l16) * 64 + 32 + quad * 8);
    f32x4 oacc[4][4];
#pragma unroll
    for (int mt = 0; mt < 4; ++mt)
#pragma unroll
        for (int nt = 0; nt < 4; ++nt)
#pragma unroll
            for (int r = 0; r < 4; ++r) oacc[mt][nt][r] = 0.f;
    float lsum[4] = {0.f, 0.f, 0.f, 0.f};
    const f32x4 zero4 = {0.f, 0.f, 0.f, 0.f};
    {
        const u16* gp = fg + fg_base +
            (size_t)(kt0 * 128 + (2 * w) * 16 + l16) * 64 + quad * 8;
        ASYNC_CP16(gp, &fl[0][(2 * w) * 512]);
        ASYNC_CP16(gp + 16 * 64, &fl[0][(2 * w + 1) * 512]);
    }
    for (int it = 0; it < nkt; ++it) {
        const int kt  = kt0 + it;
        const int buf = it & 1;
        __syncthreads();
        bf16x8 vbr[4][4];
#pragma unroll
        for (int nt = 0; nt < 4; ++nt)
#pragma unroll
            for (int kh = 0; kh < 4; ++kh)
                vbr[nt][kh] = *reinterpret_cast<const bf16x8*>(
                    hmt + vfrag_off(b, w * 4 + nt, kt * 4 + kh, quad, l16));
        if (it + 1 < nkt) {
            const u16* gp = fg + fg_base +
                (size_t)((kt + 1) * 128 + (2 * w) * 16 + l16) * 64 + quad * 8;
            ASYNC_CP16(gp, &fl[buf ^ 1][(2 * w) * 512]);
            ASYNC_CP16(gp + 16 * 64, &fl[buf ^ 1][(2 * w + 1) * 512]);
        }
        f32x4 sacc[8];
#pragma unroll
        for (int ct = 0; ct < 8; ++ct) {
            bf16x8 fb = *reinterpret_cast<const bf16x8*>(
                &fl[buf][ct * 512 + quad * 128 + l16 * 8]);
            sacc[ct] = __builtin_amdgcn_mfma_f32_16x16x32_bf16(
                gfrag, fb, zero4, 0, 0, 0);
        }
#pragma unroll
        for (int ct = 0; ct < 8; ++ct) {
#pragma unroll
            for (int r = 0; r < 4; ++r) {
                float p = __builtin_amdgcn_exp2f(sacc[ct][r]);
                lsum[r] += p;
                int row = w * 16 + quad * 4 + r;
                int key = ct * 16 + l16;
                pl[(key >> 3) * 512 + row * 8 + (key & 7)] = f2bf(p);
            }
        }
        __syncthreads();
#pragma unroll
        for (int kh = 0; kh < 4; ++kh) {
            bf16x8 pa[4];
#pragma unroll
            for (int mt = 0; mt < 4; ++mt)
                pa[mt] = *reinterpret_cast<const bf16x8*>(
                    &pl[(kh * 4 + quad) * 512 + (mt * 16 + l16) * 8]);
#pragma unroll
            for (int nt = 0; nt < 4; ++nt)
#pragma unroll
                for (int mt = 0; mt < 4; ++mt)
                    oacc[mt][nt] = __builtin_amdgcn_mfma_f32_16x16x32_bf16(
                        pa[mt], vbr[nt][kh], oacc[mt][nt], 0, 0, 0);
        }
    }
#pragma unroll
    for (int r = 0; r < 4; ++r) {
        float s = lsum[r];
        s += __shfl_xor(s, 1);
        s += __shfl_xor(s, 2);
        s += __shfl_xor(s, 4);
        s += __shfl_xor(s, 8);
        lsum[r] = s;
    }
    if (l16 == 0) {
#pragma unroll
        for (int r = 0; r < 4; ++r)
            lpart[((size_t)ks << 14) + b * 4096 + qt * 64 + w * 16 +
                  quad * 4 + r] = lsum[r];
    }
#pragma unroll
    for (int mt = 0; mt < 4; ++mt) {
        const int row16 = b * 256 + qt * 4 + mt;
#pragma unroll
        for (int nt = 0; nt < 4; ++nt) {
            int ksc = w * 2 + (nt >> 1);
            int qc  = (nt & 1) * 2 + (l16 >> 3);
            u16* op = obf + ((size_t)ks << 22) +
                (((size_t)row16 * 8 + ksc) << 9) + (qc << 7) + (l16 & 7);
#pragma unroll
            for (int r = 0; r < 4; ++r)
                op[(quad * 4 + r) * 8] = f2bf(oacc[mt][nt][r]);
        }
    }
}

// ---------------------------------------------------------------------------
// attn8 (proven 52.6us, setprio variant R13 measured null -> reverted):
// 128-row q-tiles, S=4, swizzled hmt V loads, raw oacc + lpart epilogue.
// ---------------------------------------------------------------------------
__global__ __launch_bounds__(256, 2) void attn8(
    const u16* __restrict__ fg, const u16* __restrict__ hmt,
    u16* __restrict__ obf, float* __restrict__ lpart, int ksl)
{
    __shared__ u16 fl[2][4096];
    __shared__ u16 pl[16 * 1024];
    const int t    = threadIdx.x;
    const int w    = t >> 6;
    const int lane = t & 63;
    const int quad = lane >> 4;
    const int l16  = lane & 15;
    const int u   = blockIdx.x;
    const int xcd = u & 7;
    const int b   = xcd >> 1;
    const int v   = ((u >> 3) << 1) | (xcd & 1);
    const int qt  = v >> ksl;
    const int ks  = v & ((1 << ksl) - 1);
    const int nkt = 32 >> ksl;
    const int kt0 = ks * nkt;
    const size_t fg_base = (size_t)b * 4096 * 64;
    bf16x8 gfrag[2];
#pragma unroll
    for (int h2 = 0; h2 < 2; ++h2)
        gfrag[h2] = *reinterpret_cast<const bf16x8*>(
            fg + fg_base +
            (size_t)(qt * 128 + w * 32 + h2 * 16 + l16) * 64 + 32 + quad * 8);
    f32x4 oacc[8][4];
#pragma unroll
    for (int mt = 0; mt < 8; ++mt)
#pragma unroll
        for (int nt = 0; nt < 4; ++nt)
#pragma unroll
            for (int r = 0; r < 4; ++r) oacc[mt][nt][r] = 0.f;
    float lsum[2][4] = {{0.f, 0.f, 0.f, 0.f}, {0.f, 0.f, 0.f, 0.f}};
    const f32x4 zero4 = {0.f, 0.f, 0.f, 0.f};
    {
        const u16* gp = fg + fg_base +
            (size_t)(kt0 * 128 + (2 * w) * 16 + l16) * 64 + quad * 8;
        ASYNC_CP16(gp, &fl[0][(2 * w) * 512]);
        ASYNC_CP16(gp + 16 * 64, &fl[0][(2 * w + 1) * 512]);
    }
    for (int it = 0; it < nkt; ++it) {
        const int kt  = kt0 + it;
        const int buf = it & 1;
        __syncthreads();   // B1
        if (it + 1 < nkt) {
            const u16* gp = fg + fg_base +
                (size_t)((kt + 1) * 128 + (2 * w) * 16 + l16) * 64 + quad * 8;
            ASYNC_CP16(gp, &fl[buf ^ 1][(2 * w) * 512]);
            ASYNC_CP16(gp + 16 * 64, &fl[buf ^ 1][(2 * w + 1) * 512]);
        }
        // QK row-half 0
        {
            f32x4 sacc[8];
#pragma unroll
            for (int ct = 0; ct < 8; ++ct) {
                bf16x8 fb = *reinterpret_cast<const bf16x8*>(
                    &fl[buf][ct * 512 + quad * 128 + l16 * 8]);
                sacc[ct] = __builtin_amdgcn_mfma_f32_16x16x32_bf16(
                    gfrag[0], fb, zero4, 0, 0, 0);
            }
#pragma unroll
            for (int ct = 0; ct < 8; ++ct) {
#pragma unroll
                for (int r = 0; r < 4; ++r) {
                    float p = __builtin_amdgcn_exp2f(sacc[ct][r]);
                    lsum[0][r] += p;
                    int row = w * 32 + quad * 4 + r;
                    int key = ct * 16 + l16;
                    pl[(key >> 3) * 1024 + row * 8 + (key & 7)] = f2bf(p);
                }
            }
        }
        // V kh-pair A
        bf16x8 va[4][2];
#pragma unroll
        for (int nt = 0; nt < 4; ++nt)
#pragma unroll
            for (int j = 0; j < 2; ++j)
                va[nt][j] = *reinterpret_cast<const bf16x8*>(
                    hmt + vfrag_off(b, w * 4 + nt, kt * 4 + j, quad, l16));
        // QK row-half 1
        {
            f32x4 sacc[8];
#pragma unroll
            for (int ct = 0; ct < 8; ++ct) {
                bf16x8 fb = *reinterpret_cast<const bf16x8*>(
                    &fl[buf][ct * 512 + quad * 128 + l16 * 8]);
                sacc[ct] = __builtin_amdgcn_mfma_f32_16x16x32_bf16(
                    gfrag[1], fb, zero4, 0, 0, 0);
            }
#pragma unroll
            for (int ct = 0; ct < 8; ++ct) {
#pragma unroll
                for (int r = 0; r < 4; ++r) {
                    float p = __builtin_amdgcn_exp2f(sacc[ct][r]);
                    lsum[1][r] += p;
                    int row = w * 32 + 16 + quad * 4 + r;
                    int key = ct * 16 + l16;
                    pl[(key >> 3) * 1024 + row * 8 + (key & 7)] = f2bf(p);
                }
            }
        }
        __syncthreads();   // B2
        // PV kh-pair A
#pragma unroll
        for (int kh = 0; kh < 2; ++kh) {
#pragma unroll
            for (int mh = 0; mh < 2; ++mh) {
                bf16x8 pa[4];
#pragma unroll
                for (int m = 0; m < 4; ++m)
                    pa[m] = *reinterpret_cast<const bf16x8*>(
                        &pl[(kh * 4 + quad) * 1024 +
                            ((mh * 4 + m) * 16 + l16) * 8]);
#pragma unroll
                for (int nt = 0; nt < 4; ++nt)
#pragma unroll
                    for (int m = 0; m < 4; ++m)
                        oacc[mh * 4 + m][nt] =
                            __builtin_amdgcn_mfma_f32_16x16x32_bf16(
                                pa[m], va[nt][kh], oacc[mh * 4 + m][nt],
                                0, 0, 0);
            }
        }
        // V kh-pair B
        bf16x8 vb[4][2];
#pragma unroll
        for (int nt = 0; nt < 4; ++nt)
#pragma unroll
            for (int j = 0; j < 2; ++j)
                vb[nt][j] = *reinterpret_cast<const bf16x8*>(
                    hmt + vfrag_off(b, w * 4 + nt, kt * 4 + 2 + j, quad, l16));
#pragma unroll
        for (int kh = 2; kh < 4; ++kh) {
#pragma unroll
            for (int mh = 0; mh < 2; ++mh) {
                bf16x8 pa[4];
#pragma unroll
                for (int m = 0; m < 4; ++m)
                    pa[m] = *reinterpret_cast<const bf16x8*>(
                        &pl[(kh * 4 + quad) * 1024 +
                            ((mh * 4 + m) * 16 + l16) * 8]);
#pragma unroll
                for (int nt = 0; nt < 4; ++nt)
#pragma unroll
                    for (int m = 0; m < 4; ++m)
                        oacc[mh * 4 + m][nt] =
                            __builtin_amdgcn_mfma_f32_16x16x32_bf16(
                                pa[m], vb[nt][kh - 2], oacc[mh * 4 + m][nt],
                                0, 0, 0);
            }
        }
    }
#pragma unroll
    for (int h2 = 0; h2 < 2; ++h2) {
#pragma unroll
        for (int r = 0; r < 4; ++r) {
            float s = lsum[h2][r];
            s += __shfl_xor(s, 1);
            s += __shfl_xor(s, 2);
            s += __shfl_xor(s, 4);
            s += __shfl_xor(s, 8);
            lsum[h2][r] = s;
        }
    }
    if (l16 == 0) {
#pragma unroll
        for (int h2 = 0; h2 < 2; ++h2)
#pragma unroll
            for (int r = 0; r < 4; ++r) {
                int row = w * 32 + h2 * 16 + quad * 4 + r;
                lpart[((size_t)ks << 14) + b * 4096 + qt * 128 + row] =
                    lsum[h2][r];
            }
    }
#pragma unroll
    for (int mt = 0; mt < 8; ++mt) {
        const int row16 = b * 256 + qt * 8 + mt;
#pragma unroll
        for (int nt = 0; nt < 4; ++nt) {
            int ksc = w * 2 + (nt >> 1);
            int qc  = (nt & 1) * 2 + (l16 >> 3);
            u16* op = obf + ((size_t)ks << 22) +
                (((size_t)row16 * 8 + ksc) << 9) + (qc << 7) + (l16 & 7);
#pragma unroll
            for (int r = 0; r < 4; ++r)
                op[(quad * 4 + r) * 8] = f2bf(oacc[mt][nt][r]);
        }
    }
}

// ---------------------------------------------------------------------------
// final v9: out = x + (Sigma_s O_raw_s) @ Wv * inv[row] + bv.
// obf LDS-staged (coalesced); plain-sum combine; single MFMA set; bfrag
// 1KB contiguous/wave from swizzled wT (row-groups 20..35).
// ---------------------------------------------------------------------------
__global__ __launch_bounds__(256) void final_mfma9(
    const u16* __restrict__ obf, const float* __restrict__ lpart, int S,
    const u16* __restrict__ wT, const float* __restrict__ bvv,
    const float* __restrict__ x, float* __restrict__ out)
{
    __shared__ u16 ol[16384];
    __shared__ float linv[16];
    const int t    = threadIdx.x;
    const int w    = t >> 6;
    const int lane = t & 63;
    const int quad = lane >> 4;
    const int l16  = lane & 15;
    const int m0   = blockIdx.x * 16;
    const int wb   = w * 64;

    const int ni = S * 2;
    for (int i = 0; i < ni; ++i) {
        int gi = w * ni + i;
        int s  = gi >> 3;
        int ks = gi & 7;
        const u16* gp = obf + ((size_t)s << 22) +
            (((size_t)(m0 >> 4) * 8 + ks) << 9) + lane * 8;
        ASYNC_CP16(gp, &ol[gi * 512]);
    }
    if (t < 16) {
        float tot = 0.f;
#pragma unroll
        for (int s = 0; s < 4; ++s)
            if (s < S) tot += lpart[((size_t)s << 14) + m0 + t];
        linv[t] = 1.f / tot;
    }
    __syncthreads();

    f32x4 acc[4];
#pragma unroll
    for (int nt = 0; nt < 4; ++nt)
#pragma unroll
        for (int r = 0; r < 4; ++r) acc[nt][r] = 0.f;

#pragma unroll 2
    for (int ks = 0; ks < 8; ++ks) {
        bf16x8 afrag;
        {
            bf16x8 v0 = *reinterpret_cast<const bf16x8*>(
                &ol[ks * 512 + lane * 8]);
            if (S == 1) {
                afrag = v0;
            } else {
                float tacc[8];
#pragma unroll
                for (int j = 0; j < 8; ++j) tacc[j] = bf2f(v0[j]);
#pragma unroll
                for (int s = 1; s < 4; ++s) {
                    if (s < S) {
                        bf16x8 vs = *reinterpret_cast<const bf16x8*>(
                            &ol[(s * 8 + ks) * 512 + lane * 8]);
#pragma unroll
                        for (int j = 0; j < 8; ++j) tacc[j] += bf2f(vs[j]);
                    }
                }
#pragma unroll
                for (int j = 0; j < 8; ++j) afrag[j] = (short)f2bf(tacc[j]);
            }
        }
#pragma unroll
        for (int nt = 0; nt < 4; ++nt) {
            bf16x8 bfrag = *reinterpret_cast<const bf16x8*>(
                wT + wfrag_off(20 + w * 4 + nt, ks, quad, l16));
            acc[nt] = __builtin_amdgcn_mfma_f32_16x16x32_bf16(
                afrag, bfrag, acc[nt], 0, 0, 0);
        }
    }

#pragma unroll
    for (int nt = 0; nt < 4; ++nt) {
        int col = wb + nt * 16 + l16;
        float bias = bvv[col];
        int row = m0 + quad * 4;
#pragma unroll
        for (int r = 0; r < 4; ++r) {
            size_t off = (size_t)(row + r) * 256 + col;
            out[off] = acc[nt][r] * linv[quad * 4 + r] + bias + x[off];
        }
    }
}

// ---------------------------------------------------------------------------
extern "C" void kernel_launch(void* const* d_in, const int* in_sizes, int n_in,
                              void* d_out, int out_size, void* d_ws, size_t ws_size,
                              hipStream_t stream)
{
    const float* x  = (const float*)d_in[0];
    const float* Wf = (const float*)d_in[1];
    const float* bf = (const float*)d_in[2];
    const float* Wg = (const float*)d_in[3];
    const float* bg = (const float*)d_in[4];
    const float* Wh = (const float*)d_in[5];
    const float* bh = (const float*)d_in[6];
    const float* Wv = (const float*)d_in[7];
    const float* bv = (const float*)d_in[8];
    float* out = (float*)d_out;

    const int M = 16384;

    const size_t base_b = (size_t)M * 64 * 2 + (size_t)4 * 256 * 4096 * 2 +
                          (size_t)576 * 256 * 2;
    const size_t per_s  = (size_t)M * 4 + (size_t)M * 256 * 2;
    int ksl = 0;
    if (ws_size >= base_b + 4 * per_s)      ksl = 2;
    else if (ws_size >= base_b + 2 * per_s) ksl = 1;
    const int S = 1 << ksl;

    u16*   fgbuf = (u16*)d_ws;
    u16*   hmt   = fgbuf + (size_t)M * 64;
    u16*   wT    = hmt + (size_t)4 * 256 * 4096;
    float* lpart = (float*)(wT + (size_t)576 * 256);
    u16*   obf   = (u16*)(lpart + (size_t)S * M);

    dim3 blk(256);

    prep_w3<<<dim3(18), blk, 0, stream>>>(Wf, Wg, Wh, Wv, wT);
    proj_mfma3<<<dim3(M / 16), blk, 0, stream>>>(x, wT, bf, bg, bh, fgbuf, hmt);
    if (ksl == 2)
        attn8<<<dim3(512), blk, 0, stream>>>(fgbuf, hmt, obf, lpart, ksl);
    else
        attn5<<<dim3(256 * S), blk, 0, stream>>>(fgbuf, hmt, obf, lpart, ksl);
    final_mfma9<<<dim3(M / 16), blk, 0, stream>>>(
        obf, lpart, S, wT, bv, x, out);
}